// Round 1
// baseline (1140.512 us; speedup 1.0000x reference)
//
#include <hip/hip_runtime.h>
#include <hip/hip_bf16.h>

#define BB 4
#define MM 8192
#define NN 512
#define DD 512
#define GG 33
#define TOPK 20
#define NITER 5
#define CH 256          // rows per col-partial chunk
#define NCH (MM / CH)   // 32 chunks

// ---------------- GEMM: C[b][m][n] = scale * sum_k X[b][m][k]*Y[b][n][k] ----------------
__global__ __launch_bounds__(256) void gemm_nt(
    const float* __restrict__ X, const float* __restrict__ Y,
    float* __restrict__ C, int K, float scale)
{
    __shared__ float As[16][68];
    __shared__ float Bs[16][68];
    const int bm = blockIdx.x * 64;
    const int bn = blockIdx.y * 64;
    const int b  = blockIdx.z;
    const float* Xb = X + (size_t)b * MM * K;
    const float* Yb = Y + (size_t)b * NN * K;
    const int tid  = threadIdx.x;
    const int row4 = tid >> 2;          // 0..63
    const int kq   = (tid & 3) << 2;    // 0,4,8,12
    const int tx = tid & 15, ty = tid >> 4;
    float acc[4][4] = {};
    for (int k0 = 0; k0 < K; k0 += 16) {
#pragma unroll
        for (int j = 0; j < 4; ++j) {
            int k = k0 + kq + j;
            As[kq + j][row4] = (k < K) ? Xb[(size_t)(bm + row4) * K + k] : 0.0f;
            Bs[kq + j][row4] = (k < K) ? Yb[(size_t)(bn + row4) * K + k] : 0.0f;
        }
        __syncthreads();
#pragma unroll
        for (int k = 0; k < 16; ++k) {
            const float4 a4 = *(const float4*)&As[k][ty << 2];
            const float4 b4 = *(const float4*)&Bs[k][tx << 2];
            const float a[4]  = {a4.x, a4.y, a4.z, a4.w};
            const float bv[4] = {b4.x, b4.y, b4.z, b4.w};
#pragma unroll
            for (int i = 0; i < 4; ++i)
#pragma unroll
                for (int j = 0; j < 4; ++j)
                    acc[i][j] = fmaf(a[i], bv[j], acc[i][j]);
        }
        __syncthreads();
    }
    float* Cb = C + ((size_t)b * MM + bm) * NN + bn;
#pragma unroll
    for (int i = 0; i < 4; ++i) {
        float4 v = make_float4(acc[i][0] * scale, acc[i][1] * scale,
                               acc[i][2] * scale, acc[i][3] * scale);
        *(float4*)&Cb[(size_t)(ty * 4 + i) * NN + (tx << 2)] = v;
    }
}

// ---------------- row LSE: r[b,m] = lse_n(A[b,m,n] - c[b,n]) ----------------
// grid: (B*M/4, 2); 4 waves/block, one row per wave. blockIdx.y picks tensor.
__global__ __launch_bounds__(256) void row_lse(
    const float* __restrict__ Af, const float* __restrict__ Ag,
    const float* __restrict__ cf, const float* __restrict__ cg,
    float* __restrict__ rf, float* __restrict__ rg)
{
    const int wave = threadIdx.x >> 6;
    const int lane = threadIdx.x & 63;
    const int row  = (blockIdx.x << 2) + wave;   // 0..B*M-1
    const float* A = blockIdx.y ? Ag : Af;
    const float* c = blockIdx.y ? cg : cf;
    float* r       = blockIdx.y ? rg : rf;
    const int b = row >> 13;
    const float* Ar = A + (size_t)row * NN;
    const float* cb = c + (b << 9);
    float4 a0 = *(const float4*)&Ar[lane * 8];
    float4 a1 = *(const float4*)&Ar[lane * 8 + 4];
    float4 c0 = *(const float4*)&cb[lane * 8];
    float4 c1 = *(const float4*)&cb[lane * 8 + 4];
    float v[8] = {a0.x - c0.x, a0.y - c0.y, a0.z - c0.z, a0.w - c0.w,
                  a1.x - c1.x, a1.y - c1.y, a1.z - c1.z, a1.w - c1.w};
    float mx = v[0];
#pragma unroll
    for (int j = 1; j < 8; ++j) mx = fmaxf(mx, v[j]);
#pragma unroll
    for (int s = 32; s; s >>= 1) mx = fmaxf(mx, __shfl_xor(mx, s));
    float S = 0.f;
#pragma unroll
    for (int j = 0; j < 8; ++j) S += __expf(v[j] - mx);
#pragma unroll
    for (int s = 32; s; s >>= 1) S += __shfl_xor(S, s);
    if (lane == 0) r[row] = mx + __logf(S);
}

// ---------------- col LSE stage 1: partial (max,sum) over m-chunks ----------------
// grid: (N/256, M/CH, B*2); thread = one column n over CH rows.
__global__ __launch_bounds__(256) void col_partial(
    const float* __restrict__ Af, const float* __restrict__ Ag,
    const float* __restrict__ rf, const float* __restrict__ rg,
    float2* __restrict__ pf, float2* __restrict__ pg)
{
    const int t = blockIdx.z & 1;
    const int b = blockIdx.z >> 1;
    const float* A = t ? Ag : Af;
    const float* r = t ? rg : rf;
    float2* p      = t ? pg : pf;
    const int n  = (blockIdx.x << 8) + threadIdx.x;
    const int m0 = blockIdx.y * CH;
    const float* Ab = A + ((size_t)b * MM + m0) * NN + n;
    const float* rb = r + (b << 13) + m0;
    float mx = -INFINITY, S = 0.f;
#pragma unroll 8
    for (int mm = 0; mm < CH; ++mm) {
        float v  = Ab[(size_t)mm * NN] - rb[mm];
        float nm = fmaxf(mx, v);
        S = S * __expf(mx - nm) + __expf(v - nm);
        mx = nm;
    }
    p[(((b * NCH) + blockIdx.y) << 9) + n] = make_float2(mx, S);
}

// ---------------- col LSE stage 2: combine chunks -> c[b,n] ----------------
__global__ __launch_bounds__(256) void col_combine(
    const float2* __restrict__ pf, const float2* __restrict__ pg,
    float* __restrict__ cf, float* __restrict__ cg)
{
    const int idx = blockIdx.x * 256 + threadIdx.x;  // 0..2*B*N-1
    const int t  = idx >> 11;
    const int bn = idx & 2047;
    const int b = bn >> 9, n = bn & 511;
    const float2* p = t ? pg : pf;
    float mx = -INFINITY;
    float2 loc[NCH];
#pragma unroll
    for (int ch = 0; ch < NCH; ++ch) {
        loc[ch] = p[((b * NCH + ch) << 9) + n];
        mx = fmaxf(mx, loc[ch].x);
    }
    float S = 0.f;
#pragma unroll
    for (int ch = 0; ch < NCH; ++ch) S += loc[ch].y * __expf(loc[ch].x - mx);
    (t ? cg : cf)[bn] = mx + __logf(S);
}

// ---------------- final: s = Af+Ag-cf-cg, top-20, softmax weights, gather ----------------
__global__ __launch_bounds__(256) void final_k(
    const float* __restrict__ Af, const float* __restrict__ Ag,
    const float* __restrict__ cf, const float* __restrict__ cg,
    const float* __restrict__ node_feats, const float* __restrict__ node_fpfhs,
    const float* __restrict__ xyz_feats,  const float* __restrict__ xyz_fpfhs,
    float* __restrict__ out)
{
    __shared__ float sv[NN];
    __shared__ float wE[TOPK];
    __shared__ int   wI[TOPK];
    __shared__ float wInv;
    const int row = blockIdx.x;          // b*M+m
    const int b = row >> 13;
    const int tid = threadIdx.x;
    const float* ArF = Af + (size_t)row * NN;
    const float* ArG = Ag + (size_t)row * NN;
    const float* cfb = cf + (b << 9);
    const float* cgb = cg + (b << 9);
    for (int n = tid; n < NN; n += 256)
        sv[n] = ArF[n] + ArG[n] - cfb[n] - cgb[n];
    __syncthreads();
    if (tid < 64) {
        const int lane = tid;
        float v[8];
#pragma unroll
        for (int j = 0; j < 8; ++j) v[j] = sv[lane + (j << 6)];
        float mx0 = 0.f, Ssum = 0.f;
        for (int it = 0; it < TOPK; ++it) {
            float bv2 = v[0]; int bi = lane;
#pragma unroll
            for (int j = 1; j < 8; ++j)
                if (v[j] > bv2) { bv2 = v[j]; bi = lane + (j << 6); }
#pragma unroll
            for (int s = 32; s; s >>= 1) {
                float ov = __shfl_xor(bv2, s);
                int   oi = __shfl_xor(bi, s);
                if (ov > bv2 || (ov == bv2 && oi < bi)) { bv2 = ov; bi = oi; }
            }
            if (it == 0) mx0 = bv2;
            float e = __expf(bv2 - mx0);
            Ssum += e;
            if (lane == (bi & 63)) v[bi >> 6] = -INFINITY;
            if (lane == 0) { wE[it] = e; wI[it] = bi; }
        }
        if (lane == 0) wInv = 1.0f / Ssum;
    }
    __syncthreads();
    const float inv = wInv;
    const float* xf = xyz_feats + (size_t)row * DD;
    float* of = out + (size_t)row * DD;
#pragma unroll
    for (int rep = 0; rep < 2; ++rep) {
        int d = tid + rep * 256;
        float acc = 0.f;
#pragma unroll
        for (int i = 0; i < TOPK; ++i)
            acc = fmaf(wE[i], node_feats[((size_t)(b << 9) + wI[i]) * DD + d], acc);
        of[d] = (acc * inv + xf[d]) * 0.5f;
    }
    if (tid < GG) {
        const float* xg = xyz_fpfhs + (size_t)row * GG;
        float* og = out + (size_t)BB * MM * DD + (size_t)row * GG;
        float acc = 0.f;
#pragma unroll
        for (int i = 0; i < TOPK; ++i)
            acc = fmaf(wE[i], node_fpfhs[((size_t)(b << 9) + wI[i]) * GG + tid], acc);
        og[tid] = (acc * inv + xg[tid]) * 0.5f;
    }
}

extern "C" void kernel_launch(void* const* d_in, const int* in_sizes, int n_in,
                              void* d_out, int out_size, void* d_ws, size_t ws_size,
                              hipStream_t stream)
{
    (void)in_sizes; (void)n_in; (void)out_size; (void)ws_size;
    const float* node_feats = (const float*)d_in[2];
    const float* xyz_feats  = (const float*)d_in[3];
    const float* node_fpfhs = (const float*)d_in[4];
    const float* xyz_fpfhs  = (const float*)d_in[5];

    float* ws = (float*)d_ws;
    float* Af = ws;                                 // B*M*N
    float* Ag = Af + (size_t)BB * MM * NN;          // B*M*N
    float* cf = Ag + (size_t)BB * MM * NN;          // B*N
    float* cg = cf + BB * NN;                       // B*N
    float* rf = cg + BB * NN;                       // B*M
    float* rg = rf + BB * MM;                       // B*M
    float2* pf = (float2*)(rg + BB * MM);           // B*NCH*N
    float2* pg = pf + (size_t)BB * NCH * NN;        // B*NCH*N
    float* out = (float*)d_out;

    // c potentials start at 0 (cf,cg contiguous)
    hipMemsetAsync(cf, 0, 2 * BB * NN * sizeof(float), stream);

    dim3 gg(MM / 64, NN / 64, BB);
    gemm_nt<<<gg, 256, 0, stream>>>(xyz_feats, node_feats, Af, 512, 0.04419417382415922f);
    gemm_nt<<<gg, 256, 0, stream>>>(xyz_fpfhs, node_fpfhs, Ag, 33, 0.17407765595569785f);

    for (int it = 0; it < NITER; ++it) {
        row_lse<<<dim3(BB * MM / 4, 2), 256, 0, stream>>>(Af, Ag, cf, cg, rf, rg);
        col_partial<<<dim3(NN / 256, MM / CH, BB * 2), 256, 0, stream>>>(Af, Ag, rf, rg, pf, pg);
        col_combine<<<dim3(2 * BB * NN / 256), 256, 0, stream>>>(pf, pg, cf, cg);
    }
    final_k<<<dim3(BB * MM), 256, 0, stream>>>(Af, Ag, cf, cg, node_feats, node_fpfhs,
                                               xyz_feats, xyz_fpfhs, out);
}

// Round 4
// 792.362 us; speedup vs baseline: 1.4394x; 1.4394x over previous
//
#include <hip/hip_runtime.h>
#include <hip/hip_bf16.h>
#include <hip/hip_fp16.h>

#define BB 4
#define MM 8192
#define NN 512
#define DD 512
#define GG 33
#define TOPK 20
#define NITER 5
#define SROWS 16
#define NCH (MM / SROWS)   // 512 chunks

using short8 = __attribute__((ext_vector_type(8))) short;
using f32x4  = __attribute__((ext_vector_type(4))) float;

#define GLOBAL_AS __attribute__((address_space(1)))
#define LDS_AS    __attribute__((address_space(3)))

#define LO_SCALE 4096.0f
#define LO_INV   (1.0f / 4096.0f)

__device__ __forceinline__ unsigned short f2h(float f) {
    __half h = __float2half(f);   // round-to-nearest-even
    return *(unsigned short*)&h;
}
__device__ __forceinline__ float h2f(unsigned short u) {
    __half h = *(__half*)&u;
    return __half2float(h);
}

// ---- split fp32 -> [hi(512) | lo*4096(512)] f16 rows of 1024 ----
// hi = f16(x); lo' = f16((x-hi)*4096)  -> all limbs normal-range f16, recon err ~2^-24|x|
__global__ __launch_bounds__(256) void split_hilo(
    const float* __restrict__ X, unsigned short* __restrict__ Xe)
{
    const size_t i = (size_t)blockIdx.x * 256 + threadIdx.x;  // one thread = 4 elems
    const size_t row = i >> 7;
    const int   k4  = (int)(i & 127) << 2;
    const float4 x = *(const float4*)&X[(row << 9) + k4];
    ushort4 h, l;
    h.x = f2h(x.x); h.y = f2h(x.y); h.z = f2h(x.z); h.w = f2h(x.w);
    l.x = f2h((x.x - h2f(h.x)) * LO_SCALE);
    l.y = f2h((x.y - h2f(h.y)) * LO_SCALE);
    l.z = f2h((x.z - h2f(h.z)) * LO_SCALE);
    l.w = f2h((x.w - h2f(h.w)) * LO_SCALE);
    *(ushort4*)&Xe[(row << 10) + k4] = h;
    *(ushort4*)&Xe[(row << 10) + 512 + k4] = l;
}

// ---- f16 MFMA GEMM, C = scale * (AhBh + (AhBl' + Al'Bh)/4096),  K = 512 ----
__global__ __launch_bounds__(256) void gemm_f_mfma(
    const unsigned short* __restrict__ Xe, const unsigned short* __restrict__ Ye,
    float* __restrict__ C)
{
    __shared__ unsigned short AsH[128 * 64];
    __shared__ unsigned short AsL[128 * 64];
    __shared__ unsigned short BsH[128 * 64];
    __shared__ unsigned short BsL[128 * 64];
    const int tid = threadIdx.x;
    const int wid = tid >> 6, lane = tid & 63;
    const int bm = blockIdx.x << 7;
    const int bn = blockIdx.y << 7;
    const int b  = blockIdx.z;
    const unsigned short* XeB = Xe + (((size_t)b * MM + bm) << 10);
    const unsigned short* YeB = Ye + (((size_t)b * NN + bn) << 10);

    f32x4 acc1[4][4];   // Ah*Bh
    f32x4 acc2[4][4];   // Ah*Bl' + Al'*Bh   (carries 2^12 factor)
#pragma unroll
    for (int i = 0; i < 4; ++i)
#pragma unroll
        for (int j = 0; j < 4; ++j) {
            acc1[i][j] = (f32x4){0.f, 0.f, 0.f, 0.f};
            acc2[i][j] = (f32x4){0.f, 0.f, 0.f, 0.f};
        }

    const int wr = (wid >> 1) << 6;       // wave row origin: 0 / 64
    const int wc = (wid & 1) << 6;        // wave col origin: 0 / 64
    const int l15 = lane & 15;
    const int xorv = (lane & 7) << 4;     // (row&7)<<4 since row%8 == lane%8
    const int khalf = (lane >> 4) << 4;   // 16B group within 64B half
    int rbA[4], rbB[4];
#pragma unroll
    for (int i = 0; i < 4; ++i) {
        rbA[i] = (wr + i * 16 + l15) << 7;   // row * 128 bytes
        rbB[i] = (wc + i * 16 + l15) << 7;
    }

    // per-thread staging geometry (16B chunks, inverse-swizzled source)
    int srow[4], scs[4], sldsb[4];
#pragma unroll
    for (int q = 0; q < 4; ++q) {
        const int cl = q * 256 + tid;
        srow[q]  = cl >> 3;
        scs[q]   = ((cl & 7) ^ (srow[q] & 7)) << 3;
        sldsb[q] = (q * 256 + wid * 64) << 4;   // wave-uniform LDS byte base
    }

    for (int st = 0; st < 8; ++st) {
        const int kin = st << 6;
#pragma unroll
        for (int q = 0; q < 4; ++q) {
            const size_t rb = (size_t)srow[q] << 10;
            __builtin_amdgcn_global_load_lds(
                (const GLOBAL_AS void*)(XeB + rb + kin + scs[q]),
                (LDS_AS void*)((char*)AsH + sldsb[q]), 16, 0, 0);
            __builtin_amdgcn_global_load_lds(
                (const GLOBAL_AS void*)(XeB + rb + 512 + kin + scs[q]),
                (LDS_AS void*)((char*)AsL + sldsb[q]), 16, 0, 0);
            __builtin_amdgcn_global_load_lds(
                (const GLOBAL_AS void*)(YeB + rb + kin + scs[q]),
                (LDS_AS void*)((char*)BsH + sldsb[q]), 16, 0, 0);
            __builtin_amdgcn_global_load_lds(
                (const GLOBAL_AS void*)(YeB + rb + 512 + kin + scs[q]),
                (LDS_AS void*)((char*)BsL + sldsb[q]), 16, 0, 0);
        }
        __syncthreads();
#pragma unroll
        for (int ks = 0; ks < 2; ++ks) {
            const int cb = ((ks << 6) + khalf) ^ xorv;
            short8 ah[4], bh[4], tt[4];
#pragma unroll
            for (int i = 0; i < 4; ++i) {
                ah[i] = *(const short8*)((const char*)AsH + rbA[i] + cb);
                bh[i] = *(const short8*)((const char*)BsH + rbB[i] + cb);
                tt[i] = *(const short8*)((const char*)BsL + rbB[i] + cb);
            }
#pragma unroll
            for (int i = 0; i < 4; ++i)
#pragma unroll
                for (int j = 0; j < 4; ++j) {
                    acc1[i][j] = __builtin_amdgcn_mfma_f32_16x16x32_f16(
                        ah[i], bh[j], acc1[i][j], 0, 0, 0);
                    acc2[i][j] = __builtin_amdgcn_mfma_f32_16x16x32_f16(
                        ah[i], tt[j], acc2[i][j], 0, 0, 0);
                }
#pragma unroll
            for (int i = 0; i < 4; ++i)
                tt[i] = *(const short8*)((const char*)AsL + rbA[i] + cb);
#pragma unroll
            for (int i = 0; i < 4; ++i)
#pragma unroll
                for (int j = 0; j < 4; ++j)
                    acc2[i][j] = __builtin_amdgcn_mfma_f32_16x16x32_f16(
                        tt[i], bh[j], acc2[i][j], 0, 0, 0);
        }
        __syncthreads();
    }
    const float scale = 0.04419417382415922f;
    float* Cb = C + (((size_t)b * MM) << 9);
    const int r0 = (lane >> 4) << 2;
#pragma unroll
    for (int i = 0; i < 4; ++i) {
        const int grow = bm + wr + i * 16 + r0;
#pragma unroll
        for (int j = 0; j < 4; ++j) {
            const int gcol = bn + wc + j * 16 + l15;
#pragma unroll
            for (int r = 0; r < 4; ++r)
                Cb[((size_t)(grow + r) << 9) + gcol] =
                    (acc1[i][j][r] + acc2[i][j][r] * LO_INV) * scale;
        }
    }
}

// ---- small-K fp32 GEMM (g scores, K=33) ----
__global__ __launch_bounds__(256) void gemm_nt(
    const float* __restrict__ X, const float* __restrict__ Y,
    float* __restrict__ C, int K, float scale)
{
    __shared__ float As[16][68];
    __shared__ float Bs[16][68];
    const int bm = blockIdx.x * 64;
    const int bn = blockIdx.y * 64;
    const int b  = blockIdx.z;
    const float* Xb = X + (size_t)b * MM * K;
    const float* Yb = Y + (size_t)b * NN * K;
    const int tid  = threadIdx.x;
    const int row4 = tid >> 2;
    const int kq   = (tid & 3) << 2;
    const int tx = tid & 15, ty = tid >> 4;
    float acc[4][4] = {};
    for (int k0 = 0; k0 < K; k0 += 16) {
#pragma unroll
        for (int j = 0; j < 4; ++j) {
            int k = k0 + kq + j;
            As[kq + j][row4] = (k < K) ? Xb[(size_t)(bm + row4) * K + k] : 0.0f;
            Bs[kq + j][row4] = (k < K) ? Yb[(size_t)(bn + row4) * K + k] : 0.0f;
        }
        __syncthreads();
#pragma unroll
        for (int k = 0; k < 16; ++k) {
            const float4 a4 = *(const float4*)&As[k][ty << 2];
            const float4 b4 = *(const float4*)&Bs[k][tx << 2];
            const float a[4]  = {a4.x, a4.y, a4.z, a4.w};
            const float bv[4] = {b4.x, b4.y, b4.z, b4.w};
#pragma unroll
            for (int i = 0; i < 4; ++i)
#pragma unroll
                for (int j = 0; j < 4; ++j)
                    acc[i][j] = fmaf(a[i], bv[j], acc[i][j]);
        }
        __syncthreads();
    }
    float* Cb = C + ((size_t)b * MM + bm) * NN + bn;
#pragma unroll
    for (int i = 0; i < 4; ++i) {
        float4 v = make_float4(acc[i][0] * scale, acc[i][1] * scale,
                               acc[i][2] * scale, acc[i][3] * scale);
        *(float4*)&Cb[(size_t)(ty * 4 + i) * NN + (tx << 2)] = v;
    }
}

// ---- fused sinkhorn iteration: r = lse_n(A - c) in-LDS, then col partials sum_m exp(A - r) ----
__global__ __launch_bounds__(256) void sinkhorn_fused(
    const float* __restrict__ Af, const float* __restrict__ Ag,
    const float* __restrict__ cf, const float* __restrict__ cg,
    float* __restrict__ pf, float* __restrict__ pg)
{
    __shared__ float At[SROWS][512];
    __shared__ float cs[512];
    __shared__ float rs[SROWS];
    const int t = blockIdx.z, b = blockIdx.y, ch = blockIdx.x;
    const float* __restrict__ A = t ? Ag : Af;
    const float* __restrict__ c = t ? cg : cf;
    float* __restrict__ p = t ? pg : pf;
    const int tid = threadIdx.x;
    const float* Ab = A + (((size_t)b * MM + ch * SROWS) << 9);
    cs[tid]       = c[(b << 9) + tid];
    cs[tid + 256] = c[(b << 9) + tid + 256];
#pragma unroll
    for (int q = 0; q < 8; ++q) {
        const int f = (q * 256 + tid) << 2;
        *(float4*)&((float*)At)[f] = *(const float4*)&Ab[f];
    }
    __syncthreads();
    const int wv = tid >> 6, ln = tid & 63;
#pragma unroll
    for (int rr = 0; rr < 4; ++rr) {
        const int r = wv * 4 + rr;
        const float4 x0 = *(const float4*)&At[r][ln * 8];
        const float4 x1 = *(const float4*)&At[r][ln * 8 + 4];
        const float4 c0 = *(const float4*)&cs[ln * 8];
        const float4 c1 = *(const float4*)&cs[ln * 8 + 4];
        float v[8] = {x0.x - c0.x, x0.y - c0.y, x0.z - c0.z, x0.w - c0.w,
                      x1.x - c1.x, x1.y - c1.y, x1.z - c1.z, x1.w - c1.w};
        float mx = v[0];
#pragma unroll
        for (int j = 1; j < 8; ++j) mx = fmaxf(mx, v[j]);
#pragma unroll
        for (int s = 32; s; s >>= 1) mx = fmaxf(mx, __shfl_xor(mx, s));
        float S = 0.f;
#pragma unroll
        for (int j = 0; j < 8; ++j) S += __expf(v[j] - mx);
#pragma unroll
        for (int s = 32; s; s >>= 1) S += __shfl_xor(S, s);
        if (ln == 0) rs[r] = mx + __logf(S);
    }
    __syncthreads();
    // col partials: after row norm all values <= 0, direct exp-sum is safe
    float S0 = 0.f, S1 = 0.f;
#pragma unroll
    for (int r = 0; r < SROWS; ++r) {
        const float rv = rs[r];
        S0 += __expf(At[r][tid] - rv);
        S1 += __expf(At[r][tid + 256] - rv);
    }
    float* pb = p + (((size_t)b * NCH + ch) << 9);
    pb[tid]       = S0;
    pb[tid + 256] = S1;
}

// ---- combine chunk partials -> c[b,n] = log(sum) ----
__global__ __launch_bounds__(256) void col_combine(
    const float* __restrict__ pf, const float* __restrict__ pg,
    float* __restrict__ cf, float* __restrict__ cg)
{
    __shared__ float red[8][32];
    const int blk = blockIdx.x;                       // 0..127
    const int t = blk >> 6, b = (blk >> 4) & 3, n0 = (blk & 15) << 5;
    const int ng = threadIdx.x & 31, grp = threadIdx.x >> 5;
    const float* p = (t ? pg : pf) + (((size_t)b * NCH) << 9) + n0 + ng;
    float s = 0.f;
    for (int cc = grp; cc < NCH; cc += 8) s += p[(size_t)cc << 9];
    red[grp][ng] = s;
    __syncthreads();
    if (threadIdx.x < 32) {
        float tot = 0.f;
#pragma unroll
        for (int g = 0; g < 8; ++g) tot += red[g][threadIdx.x];
        (t ? cg : cf)[(b << 9) + n0 + threadIdx.x] = __logf(tot);
    }
}

// ---- final: s = Af+Ag-cf-cg, top-20, softmax weights, gather ----
__global__ __launch_bounds__(256) void final_k(
    const float* __restrict__ Af, const float* __restrict__ Ag,
    const float* __restrict__ cf, const float* __restrict__ cg,
    const float* __restrict__ node_feats, const float* __restrict__ node_fpfhs,
    const float* __restrict__ xyz_feats,  const float* __restrict__ xyz_fpfhs,
    float* __restrict__ out)
{
    __shared__ float sv[NN];
    __shared__ float wE[TOPK];
    __shared__ int   wI[TOPK];
    __shared__ float wInv;
    const int row = blockIdx.x;          // b*M+m
    const int b = row >> 13;
    const int tid = threadIdx.x;
    const float* ArF = Af + (size_t)row * NN;
    const float* ArG = Ag + (size_t)row * NN;
    const float* cfb = cf + (b << 9);
    const float* cgb = cg + (b << 9);
    for (int n = tid; n < NN; n += 256)
        sv[n] = ArF[n] + ArG[n] - cfb[n] - cgb[n];
    __syncthreads();
    if (tid < 64) {
        const int lane = tid;
        float v[8];
#pragma unroll
        for (int j = 0; j < 8; ++j) v[j] = sv[lane + (j << 6)];
        float mx0 = 0.f, Ssum = 0.f;
        for (int it = 0; it < TOPK; ++it) {
            float bv2 = v[0]; int bi = lane;
#pragma unroll
            for (int j = 1; j < 8; ++j)
                if (v[j] > bv2) { bv2 = v[j]; bi = lane + (j << 6); }
#pragma unroll
            for (int s = 32; s; s >>= 1) {
                float ov = __shfl_xor(bv2, s);
                int   oi = __shfl_xor(bi, s);
                if (ov > bv2 || (ov == bv2 && oi < bi)) { bv2 = ov; bi = oi; }
            }
            if (it == 0) mx0 = bv2;
            float e = __expf(bv2 - mx0);
            Ssum += e;
            if (lane == (bi & 63)) v[bi >> 6] = -INFINITY;
            if (lane == 0) { wE[it] = e; wI[it] = bi; }
        }
        if (lane == 0) wInv = 1.0f / Ssum;
    }
    __syncthreads();
    const float inv = wInv;
    const float* xf = xyz_feats + (size_t)row * DD;
    float* of = out + (size_t)row * DD;
#pragma unroll
    for (int rep = 0; rep < 2; ++rep) {
        int d = tid + rep * 256;
        float acc = 0.f;
#pragma unroll
        for (int i = 0; i < TOPK; ++i)
            acc = fmaf(wE[i], node_feats[((size_t)(b << 9) + wI[i]) * DD + d], acc);
        of[d] = (acc * inv + xf[d]) * 0.5f;
    }
    if (tid < GG) {
        const float* xg = xyz_fpfhs + (size_t)row * GG;
        float* og = out + (size_t)BB * MM * DD + (size_t)row * GG;
        float acc = 0.f;
#pragma unroll
        for (int i = 0; i < TOPK; ++i)
            acc = fmaf(wE[i], node_fpfhs[((size_t)(b << 9) + wI[i]) * GG + tid], acc);
        og[tid] = (acc * inv + xg[tid]) * 0.5f;
    }
}

extern "C" void kernel_launch(void* const* d_in, const int* in_sizes, int n_in,
                              void* d_out, int out_size, void* d_ws, size_t ws_size,
                              hipStream_t stream)
{
    (void)in_sizes; (void)n_in; (void)out_size; (void)ws_size;
    const float* node_feats = (const float*)d_in[2];
    const float* xyz_feats  = (const float*)d_in[3];
    const float* node_fpfhs = (const float*)d_in[4];
    const float* xyz_fpfhs  = (const float*)d_in[5];

    float* ws = (float*)d_ws;
    float* Af = ws;                                  // B*M*N f32
    float* Ag = Af + (size_t)BB * MM * NN;           // B*M*N f32  (aliased: Xe f16 before g-gemm)
    float* cf = Ag + (size_t)BB * MM * NN;           // B*N
    float* cg = cf + BB * NN;                        // B*N
    float* pf = cg + BB * NN;                        // B*NCH*N f32 (aliased: Ye f16 before sinkhorn)
    float* pg = pf + (size_t)BB * NCH * NN;          // B*NCH*N f32
    unsigned short* Xe = (unsigned short*)Ag;        // B*M*1024 f16 == Ag bytes exactly
    unsigned short* Ye = (unsigned short*)pf;        // B*N*1024 f16 == pf bytes exactly
    float* out = (float*)d_out;

    // 1) split fp32 -> f16 hi/lo' (lo scaled 2^12 so every limb is normal-range f16)
    split_hilo<<<dim3(16384), 256, 0, stream>>>(xyz_feats, Xe);
    split_hilo<<<dim3(1024),  256, 0, stream>>>(node_feats, Ye);
    // 2) f-scores via f16 MFMA, 3-term scaled split (reads Xe/Ye, writes Af)
    gemm_f_mfma<<<dim3(MM / 128, NN / 128, BB), 256, 0, stream>>>(Xe, Ye, Af);
    // 3) g-scores fp32 (overwrites Xe region with Ag — Xe is dead now)
    gemm_nt<<<dim3(MM / 64, NN / 64, BB), 256, 0, stream>>>(
        xyz_fpfhs, node_fpfhs, Ag, 33, 0.17407765595569785f);
    // 4) c potentials start at 0
    hipMemsetAsync(cf, 0, 2 * BB * NN * sizeof(float), stream);
    // 5) sinkhorn (fused row+col per iteration; first pf write kills Ye — dead)
    for (int it = 0; it < NITER; ++it) {
        sinkhorn_fused<<<dim3(NCH, BB, 2), 256, 0, stream>>>(Af, Ag, cf, cg, pf, pg);
        col_combine<<<dim3(128), 256, 0, stream>>>(pf, pg, cf, cg);
    }
    // 6) top-k + gather
    final_k<<<dim3(BB * MM), 256, 0, stream>>>(Af, Ag, cf, cg, node_feats, node_fpfhs,
                                               xyz_feats, xyz_fpfhs, out);
}

// Round 7
// 640.399 us; speedup vs baseline: 1.7809x; 1.2373x over previous
//
#include <hip/hip_runtime.h>
#include <hip/hip_bf16.h>
#include <hip/hip_fp16.h>

#define BB 4
#define MM 8192
#define NN 512
#define DD 512
#define GG 33
#define TOPK 20
#define NITER 5
#define SROWS 16
#define NCH (MM / SROWS)   // 512 chunks

using short8 = __attribute__((ext_vector_type(8))) short;
using f32x4  = __attribute__((ext_vector_type(4))) float;

#define GLOBAL_AS __attribute__((address_space(1)))
#define LDS_AS    __attribute__((address_space(3)))

#define LO_SCALE 4096.0f
#define LO_INV   (1.0f / 4096.0f)

__device__ __forceinline__ unsigned short f2h(float f) {
    __half h = __float2half(f);   // round-to-nearest-even
    return *(unsigned short*)&h;
}
__device__ __forceinline__ float h2f(unsigned short u) {
    __half h = *(__half*)&u;
    return __half2float(h);
}

// ---- split fp32 -> [hi(512) | lo*4096(512)] f16 rows of 1024 ----
__global__ __launch_bounds__(256) void split_hilo(
    const float* __restrict__ X, unsigned short* __restrict__ Xe)
{
    const size_t i = (size_t)blockIdx.x * 256 + threadIdx.x;  // one thread = 4 elems
    const size_t row = i >> 7;
    const int   k4  = (int)(i & 127) << 2;
    const float4 x = *(const float4*)&X[(row << 9) + k4];
    ushort4 h, l;
    h.x = f2h(x.x); h.y = f2h(x.y); h.z = f2h(x.z); h.w = f2h(x.w);
    l.x = f2h((x.x - h2f(h.x)) * LO_SCALE);
    l.y = f2h((x.y - h2f(h.y)) * LO_SCALE);
    l.z = f2h((x.z - h2f(h.z)) * LO_SCALE);
    l.w = f2h((x.w - h2f(h.w)) * LO_SCALE);
    *(ushort4*)&Xe[(row << 10) + k4] = h;
    *(ushort4*)&Xe[(row << 10) + 512 + k4] = l;
}

// ---- f16 MFMA GEMM, C = scale * (AhBh + (AhBl' + Al'Bh)/4096),  K = 512 ----
__global__ __launch_bounds__(256) void gemm_f_mfma(
    const unsigned short* __restrict__ Xe, const unsigned short* __restrict__ Ye,
    float* __restrict__ C)
{
    __shared__ unsigned short AsH[128 * 64];
    __shared__ unsigned short AsL[128 * 64];
    __shared__ unsigned short BsH[128 * 64];
    __shared__ unsigned short BsL[128 * 64];
    const int tid = threadIdx.x;
    const int wid = tid >> 6, lane = tid & 63;
    const int bm = blockIdx.x << 7;
    const int bn = blockIdx.y << 7;
    const int b  = blockIdx.z;
    const unsigned short* XeB = Xe + (((size_t)b * MM + bm) << 10);
    const unsigned short* YeB = Ye + (((size_t)b * NN + bn) << 10);

    f32x4 acc1[4][4];   // Ah*Bh
    f32x4 acc2[4][4];   // Ah*Bl' + Al'*Bh   (carries 2^12 factor)
#pragma unroll
    for (int i = 0; i < 4; ++i)
#pragma unroll
        for (int j = 0; j < 4; ++j) {
            acc1[i][j] = (f32x4){0.f, 0.f, 0.f, 0.f};
            acc2[i][j] = (f32x4){0.f, 0.f, 0.f, 0.f};
        }

    const int wr = (wid >> 1) << 6;
    const int wc = (wid & 1) << 6;
    const int l15 = lane & 15;
    const int xorv = (lane & 7) << 4;
    const int khalf = (lane >> 4) << 4;
    int rbA[4], rbB[4];
#pragma unroll
    for (int i = 0; i < 4; ++i) {
        rbA[i] = (wr + i * 16 + l15) << 7;
        rbB[i] = (wc + i * 16 + l15) << 7;
    }

    int srow[4], scs[4], sldsb[4];
#pragma unroll
    for (int q = 0; q < 4; ++q) {
        const int cl = q * 256 + tid;
        srow[q]  = cl >> 3;
        scs[q]   = ((cl & 7) ^ (srow[q] & 7)) << 3;
        sldsb[q] = (q * 256 + wid * 64) << 4;
    }

    for (int st = 0; st < 8; ++st) {
        const int kin = st << 6;
#pragma unroll
        for (int q = 0; q < 4; ++q) {
            const size_t rb = (size_t)srow[q] << 10;
            __builtin_amdgcn_global_load_lds(
                (const GLOBAL_AS void*)(XeB + rb + kin + scs[q]),
                (LDS_AS void*)((char*)AsH + sldsb[q]), 16, 0, 0);
            __builtin_amdgcn_global_load_lds(
                (const GLOBAL_AS void*)(XeB + rb + 512 + kin + scs[q]),
                (LDS_AS void*)((char*)AsL + sldsb[q]), 16, 0, 0);
            __builtin_amdgcn_global_load_lds(
                (const GLOBAL_AS void*)(YeB + rb + kin + scs[q]),
                (LDS_AS void*)((char*)BsH + sldsb[q]), 16, 0, 0);
            __builtin_amdgcn_global_load_lds(
                (const GLOBAL_AS void*)(YeB + rb + 512 + kin + scs[q]),
                (LDS_AS void*)((char*)BsL + sldsb[q]), 16, 0, 0);
        }
        __syncthreads();
#pragma unroll
        for (int ks = 0; ks < 2; ++ks) {
            const int cb = ((ks << 6) + khalf) ^ xorv;
            short8 ah[4], bh[4], tt[4];
#pragma unroll
            for (int i = 0; i < 4; ++i) {
                ah[i] = *(const short8*)((const char*)AsH + rbA[i] + cb);
                bh[i] = *(const short8*)((const char*)BsH + rbB[i] + cb);
                tt[i] = *(const short8*)((const char*)BsL + rbB[i] + cb);
            }
#pragma unroll
            for (int i = 0; i < 4; ++i)
#pragma unroll
                for (int j = 0; j < 4; ++j) {
                    acc1[i][j] = __builtin_amdgcn_mfma_f32_16x16x32_f16(
                        ah[i], bh[j], acc1[i][j], 0, 0, 0);
                    acc2[i][j] = __builtin_amdgcn_mfma_f32_16x16x32_f16(
                        ah[i], tt[j], acc2[i][j], 0, 0, 0);
                }
#pragma unroll
            for (int i = 0; i < 4; ++i)
                tt[i] = *(const short8*)((const char*)AsL + rbA[i] + cb);
#pragma unroll
            for (int i = 0; i < 4; ++i)
#pragma unroll
                for (int j = 0; j < 4; ++j)
                    acc2[i][j] = __builtin_amdgcn_mfma_f32_16x16x32_f16(
                        tt[i], bh[j], acc2[i][j], 0, 0, 0);
        }
        __syncthreads();
    }
    const float scale = 0.04419417382415922f;
    float* Cb = C + (((size_t)b * MM) << 9);
    const int r0 = (lane >> 4) << 2;
#pragma unroll
    for (int i = 0; i < 4; ++i) {
        const int grow = bm + wr + i * 16 + r0;
#pragma unroll
        for (int j = 0; j < 4; ++j) {
            const int gcol = bn + wc + j * 16 + l15;
#pragma unroll
            for (int r = 0; r < 4; ++r)
                Cb[((size_t)(grow + r) << 9) + gcol] =
                    (acc1[i][j][r] + acc2[i][j][r] * LO_INV) * scale;
        }
    }
}

// ---- small-K fp32 GEMM (g scores, K=33) ----
__global__ __launch_bounds__(256) void gemm_nt(
    const float* __restrict__ X, const float* __restrict__ Y,
    float* __restrict__ C, int K, float scale)
{
    __shared__ float As[16][68];
    __shared__ float Bs[16][68];
    const int bm = blockIdx.x * 64;
    const int bn = blockIdx.y * 64;
    const int b  = blockIdx.z;
    const float* Xb = X + (size_t)b * MM * K;
    const float* Yb = Y + (size_t)b * NN * K;
    const int tid  = threadIdx.x;
    const int row4 = tid >> 2;
    const int kq   = (tid & 3) << 2;
    const int tx = tid & 15, ty = tid >> 4;
    float acc[4][4] = {};
    for (int k0 = 0; k0 < K; k0 += 16) {
#pragma unroll
        for (int j = 0; j < 4; ++j) {
            int k = k0 + kq + j;
            As[kq + j][row4] = (k < K) ? Xb[(size_t)(bm + row4) * K + k] : 0.0f;
            Bs[kq + j][row4] = (k < K) ? Yb[(size_t)(bn + row4) * K + k] : 0.0f;
        }
        __syncthreads();
#pragma unroll
        for (int k = 0; k < 16; ++k) {
            const float4 a4 = *(const float4*)&As[k][ty << 2];
            const float4 b4 = *(const float4*)&Bs[k][tx << 2];
            const float a[4]  = {a4.x, a4.y, a4.z, a4.w};
            const float bv[4] = {b4.x, b4.y, b4.z, b4.w};
#pragma unroll
            for (int i = 0; i < 4; ++i)
#pragma unroll
                for (int j = 0; j < 4; ++j)
                    acc[i][j] = fmaf(a[i], bv[j], acc[i][j]);
        }
        __syncthreads();
    }
    float* Cb = C + ((size_t)b * MM + bm) * NN + bn;
#pragma unroll
    for (int i = 0; i < 4; ++i) {
        float4 v = make_float4(acc[i][0] * scale, acc[i][1] * scale,
                               acc[i][2] * scale, acc[i][3] * scale);
        *(float4*)&Cb[(size_t)(ty * 4 + i) * NN + (tx << 2)] = v;
    }
}

// ---- fused sinkhorn iteration: r = log sum exp(A - c) in-LDS (max-free: |args| << 88),
// ---- then col partials sum_m exp(A - r) ----
__global__ __launch_bounds__(256) void sinkhorn_fused(
    const float* __restrict__ Af, const float* __restrict__ Ag,
    const float* __restrict__ cf, const float* __restrict__ cg,
    float* __restrict__ pf, float* __restrict__ pg)
{
    __shared__ float At[SROWS][512];
    __shared__ float cs[512];
    __shared__ float rs[SROWS];
    const int t = blockIdx.z, b = blockIdx.y, ch = blockIdx.x;
    const float* __restrict__ A = t ? Ag : Af;
    const float* __restrict__ c = t ? cg : cf;
    float* __restrict__ p = t ? pg : pf;
    const int tid = threadIdx.x;
    const float* Ab = A + (((size_t)b * MM + ch * SROWS) << 9);
    cs[tid]       = c[(b << 9) + tid];
    cs[tid + 256] = c[(b << 9) + tid + 256];
#pragma unroll
    for (int q = 0; q < 8; ++q) {
        const int f = (q * 256 + tid) << 2;
        *(float4*)&((float*)At)[f] = *(const float4*)&Ab[f];
    }
    __syncthreads();
    const int wv = tid >> 6, ln = tid & 63;
#pragma unroll
    for (int rr = 0; rr < 4; ++rr) {
        const int r = wv * 4 + rr;
        const float4 x0 = *(const float4*)&At[r][ln * 8];
        const float4 x1 = *(const float4*)&At[r][ln * 8 + 4];
        const float4 c0 = *(const float4*)&cs[ln * 8];
        const float4 c1 = *(const float4*)&cs[ln * 8 + 4];
        float S = __expf(x0.x - c0.x) + __expf(x0.y - c0.y)
                + __expf(x0.z - c0.z) + __expf(x0.w - c0.w)
                + __expf(x1.x - c1.x) + __expf(x1.y - c1.y)
                + __expf(x1.z - c1.z) + __expf(x1.w - c1.w);
#pragma unroll
        for (int s = 32; s; s >>= 1) S += __shfl_xor(S, s);
        if (ln == 0) rs[r] = __logf(S);
    }
    __syncthreads();
    float S0 = 0.f, S1 = 0.f;
#pragma unroll
    for (int r = 0; r < SROWS; ++r) {
        const float rv = rs[r];
        S0 += __expf(At[r][tid] - rv);
        S1 += __expf(At[r][tid + 256] - rv);
    }
    float* pb = p + (((size_t)b * NCH + ch) << 9);
    pb[tid]       = S0;
    pb[tid + 256] = S1;
}

// ---- combine chunk partials -> c[b,n] = log(sum) ----
__global__ __launch_bounds__(256) void col_combine(
    const float* __restrict__ pf, const float* __restrict__ pg,
    float* __restrict__ cf, float* __restrict__ cg)
{
    __shared__ float red[8][32];
    const int blk = blockIdx.x;                       // 0..127
    const int t = blk >> 6, b = (blk >> 4) & 3, n0 = (blk & 15) << 5;
    const int ng = threadIdx.x & 31, grp = threadIdx.x >> 5;
    const float* p = (t ? pg : pf) + (((size_t)b * NCH) << 9) + n0 + ng;
    float s = 0.f;
    for (int cc = grp; cc < NCH; cc += 8) s += p[(size_t)cc << 9];
    red[grp][ng] = s;
    __syncthreads();
    if (threadIdx.x < 32) {
        float tot = 0.f;
#pragma unroll
        for (int g = 0; g < 8; ++g) tot += red[g][threadIdx.x];
        (t ? cg : cf)[(b << 9) + n0 + threadIdx.x] = __logf(tot);
    }
}

// ---- final: one WAVE per row (4 rows/block, no barriers): s = Af+Ag-cf-cg,
// ---- top-20 via per-wave argmax butterfly, softmax weights in registers, gather ----
__global__ __launch_bounds__(256) void final_k(
    const float* __restrict__ Af, const float* __restrict__ Ag,
    const float* __restrict__ cf, const float* __restrict__ cg,
    const float* __restrict__ node_feats, const float* __restrict__ node_fpfhs,
    const float* __restrict__ xyz_feats,  const float* __restrict__ xyz_fpfhs,
    float* __restrict__ out)
{
    const int wv = threadIdx.x >> 6, ln = threadIdx.x & 63;
    const int row = (blockIdx.x << 2) + wv;   // b*M+m
    const int b = row >> 13;
    const int d0 = ln << 3;
    const float* ArF = Af + ((size_t)row << 9);
    const float* ArG = Ag + ((size_t)row << 9);
    const float* cfb = cf + (b << 9);
    const float* cgb = cg + (b << 9);
    const float4 f0 = *(const float4*)&ArF[d0];
    const float4 f1 = *(const float4*)&ArF[d0 + 4];
    const float4 g0 = *(const float4*)&ArG[d0];
    const float4 g1 = *(const float4*)&ArG[d0 + 4];
    const float4 p0 = *(const float4*)&cfb[d0];
    const float4 p1 = *(const float4*)&cfb[d0 + 4];
    const float4 q0 = *(const float4*)&cgb[d0];
    const float4 q1 = *(const float4*)&cgb[d0 + 4];
    float v[8] = {f0.x + g0.x - p0.x - q0.x, f0.y + g0.y - p0.y - q0.y,
                  f0.z + g0.z - p0.z - q0.z, f0.w + g0.w - p0.w - q0.w,
                  f1.x + g1.x - p1.x - q1.x, f1.y + g1.y - p1.y - q1.y,
                  f1.z + g1.z - p1.z - q1.z, f1.w + g1.w - p1.w - q1.w};

    float wE[TOPK]; int wI[TOPK];
    float mx0 = 0.f, Ssum = 0.f;
#pragma unroll
    for (int it = 0; it < TOPK; ++it) {
        float bv = v[0]; int bj = 0;
#pragma unroll
        for (int j = 1; j < 8; ++j)
            if (v[j] > bv) { bv = v[j]; bj = j; }
        int bi = d0 + bj;
#pragma unroll
        for (int s = 32; s; s >>= 1) {
            float ov = __shfl_xor(bv, s);
            int   oi = __shfl_xor(bi, s);
            if (ov > bv || (ov == bv && oi < bi)) { bv = ov; bi = oi; }
        }
        if (it == 0) mx0 = bv;
        const float e = __expf(bv - mx0);
        Ssum += e;
        wE[it] = e; wI[it] = bi;
        const bool mine = (bi >> 3) == ln;
        const int  rj   = bi & 7;
#pragma unroll
        for (int j = 0; j < 8; ++j)
            v[j] = (mine && rj == j) ? -INFINITY : v[j];
    }
    const float inv = 1.0f / Ssum;

    // feats gather: lane covers d0..d0+7
    float acc[8] = {0.f, 0.f, 0.f, 0.f, 0.f, 0.f, 0.f, 0.f};
#pragma unroll
    for (int i = 0; i < TOPK; ++i) {
        const float* nf = node_feats + (((size_t)((b << 9) + wI[i])) << 9) + d0;
        const float4 n0 = *(const float4*)nf;
        const float4 n1 = *(const float4*)(nf + 4);
        const float w = wE[i];
        acc[0] = fmaf(w, n0.x, acc[0]); acc[1] = fmaf(w, n0.y, acc[1]);
        acc[2] = fmaf(w, n0.z, acc[2]); acc[3] = fmaf(w, n0.w, acc[3]);
        acc[4] = fmaf(w, n1.x, acc[4]); acc[5] = fmaf(w, n1.y, acc[5]);
        acc[6] = fmaf(w, n1.z, acc[6]); acc[7] = fmaf(w, n1.w, acc[7]);
    }
    const float* xf = xyz_feats + ((size_t)row << 9) + d0;
    const float4 x0 = *(const float4*)xf;
    const float4 x1 = *(const float4*)(xf + 4);
    float* of = out + ((size_t)row << 9) + d0;
    float4 o0 = make_float4((acc[0] * inv + x0.x) * 0.5f, (acc[1] * inv + x0.y) * 0.5f,
                            (acc[2] * inv + x0.z) * 0.5f, (acc[3] * inv + x0.w) * 0.5f);
    float4 o1 = make_float4((acc[4] * inv + x1.x) * 0.5f, (acc[5] * inv + x1.y) * 0.5f,
                            (acc[6] * inv + x1.z) * 0.5f, (acc[7] * inv + x1.w) * 0.5f);
    *(float4*)of = o0;
    *(float4*)(of + 4) = o1;

    // fpfh gather: lanes 0..32
    if (ln < GG) {
        float accg = 0.f;
#pragma unroll
        for (int i = 0; i < TOPK; ++i)
            accg = fmaf(wE[i], node_fpfhs[(size_t)((b << 9) + wI[i]) * GG + ln], accg);
        const float xg = xyz_fpfhs[(size_t)row * GG + ln];
        out[(size_t)BB * MM * DD + (size_t)row * GG + ln] = (accg * inv + xg) * 0.5f;
    }
}

extern "C" void kernel_launch(void* const* d_in, const int* in_sizes, int n_in,
                              void* d_out, int out_size, void* d_ws, size_t ws_size,
                              hipStream_t stream)
{
    (void)in_sizes; (void)n_in; (void)out_size; (void)ws_size;
    const float* node_feats = (const float*)d_in[2];
    const float* xyz_feats  = (const float*)d_in[3];
    const float* node_fpfhs = (const float*)d_in[4];
    const float* xyz_fpfhs  = (const float*)d_in[5];

    float* ws = (float*)d_ws;
    float* Af = ws;                                  // B*M*N f32
    float* Ag = Af + (size_t)BB * MM * NN;           // B*M*N f32  (aliased: Xe f16 before g-gemm)
    float* cf = Ag + (size_t)BB * MM * NN;           // B*N
    float* cg = cf + BB * NN;                        // B*N
    float* pf = cg + BB * NN;                        // B*NCH*N f32 (aliased: Ye f16 before sinkhorn)
    float* pg = pf + (size_t)BB * NCH * NN;          // B*NCH*N f32
    unsigned short* Xe = (unsigned short*)Ag;        // B*M*1024 f16 == Ag bytes exactly
    unsigned short* Ye = (unsigned short*)pf;        // B*N*1024 f16 == pf bytes exactly
    float* out = (float*)d_out;

    // 1) split fp32 -> f16 hi/lo' (lo scaled 2^12 so every limb is normal-range f16)
    split_hilo<<<dim3(16384), 256, 0, stream>>>(xyz_feats, Xe);
    split_hilo<<<dim3(1024),  256, 0, stream>>>(node_feats, Ye);
    // 2) f-scores via f16 MFMA, 3-term scaled split (reads Xe/Ye, writes Af)
    gemm_f_mfma<<<dim3(MM / 128, NN / 128, BB), 256, 0, stream>>>(Xe, Ye, Af);
    // 3) g-scores fp32 (overwrites Xe region with Ag — Xe is dead now)
    gemm_nt<<<dim3(MM / 64, NN / 64, BB), 256, 0, stream>>>(
        xyz_fpfhs, node_fpfhs, Ag, 33, 0.17407765595569785f);
    // 4) c potentials start at 0
    hipMemsetAsync(cf, 0, 2 * BB * NN * sizeof(float), stream);
    // 5) sinkhorn (fused row+col per iteration; first pf write kills Ye — dead)
    for (int it = 0; it < NITER; ++it) {
        sinkhorn_fused<<<dim3(NCH, BB, 2), 256, 0, stream>>>(Af, Ag, cf, cg, pf, pg);
        col_combine<<<dim3(128), 256, 0, stream>>>(pf, pg, cf, cg);
    }
    // 6) top-k + gather: one wave per row, 4 rows per block
    final_k<<<dim3(BB * MM / 4), 256, 0, stream>>>(Af, Ag, cf, cg, node_feats, node_fpfhs,
                                                   xyz_feats, xyz_fpfhs, out);
}

// Round 8
// 554.444 us; speedup vs baseline: 2.0570x; 1.1550x over previous
//
#include <hip/hip_runtime.h>
#include <hip/hip_bf16.h>
#include <hip/hip_fp16.h>

#define BB 4
#define MM 8192
#define NN 512
#define DD 512
#define GG 33
#define TOPK 20
#define NITER 5
#define SROWS 16
#define NCH (MM / SROWS)   // 512 chunks

using short8 = __attribute__((ext_vector_type(8))) short;
using f32x4  = __attribute__((ext_vector_type(4))) float;

#define GLOBAL_AS __attribute__((address_space(1)))
#define LDS_AS    __attribute__((address_space(3)))

#define LO_SCALE 4096.0f
#define LO_INV   (1.0f / 4096.0f)

__device__ __forceinline__ unsigned short f2h(float f) {
    __half h = __float2half(f);   // round-to-nearest-even
    return *(unsigned short*)&h;
}
__device__ __forceinline__ float h2f(unsigned short u) {
    __half h = *(__half*)&u;
    return __half2float(h);
}

// DPP lane swaps within quads: 0xB1 = xor1 ([1,0,3,2]), 0x4E = xor2 ([2,3,0,1])
template<int CTRL>
__device__ __forceinline__ float dppf(float x) {
    return __int_as_float(__builtin_amdgcn_update_dpp(
        0, __float_as_int(x), CTRL, 0xF, 0xF, true));
}
template<int CTRL>
__device__ __forceinline__ int dppi(int x) {
    return __builtin_amdgcn_update_dpp(0, x, CTRL, 0xF, 0xF, true);
}

// ---- split fp32 -> [hi(512) | lo*4096(512)] f16 rows of 1024 ----
__global__ __launch_bounds__(256) void split_hilo(
    const float* __restrict__ X, unsigned short* __restrict__ Xe)
{
    const size_t i = (size_t)blockIdx.x * 256 + threadIdx.x;  // one thread = 4 elems
    const size_t row = i >> 7;
    const int   k4  = (int)(i & 127) << 2;
    const float4 x = *(const float4*)&X[(row << 9) + k4];
    ushort4 h, l;
    h.x = f2h(x.x); h.y = f2h(x.y); h.z = f2h(x.z); h.w = f2h(x.w);
    l.x = f2h((x.x - h2f(h.x)) * LO_SCALE);
    l.y = f2h((x.y - h2f(h.y)) * LO_SCALE);
    l.z = f2h((x.z - h2f(h.z)) * LO_SCALE);
    l.w = f2h((x.w - h2f(h.w)) * LO_SCALE);
    *(ushort4*)&Xe[(row << 10) + k4] = h;
    *(ushort4*)&Xe[(row << 10) + 512 + k4] = l;
}

// ---- f16 MFMA GEMM, C = scale * (AhBh + (AhBl' + Al'Bh)/4096),  K = 512 ----
__global__ __launch_bounds__(256) void gemm_f_mfma(
    const unsigned short* __restrict__ Xe, const unsigned short* __restrict__ Ye,
    float* __restrict__ C)
{
    __shared__ unsigned short AsH[128 * 64];
    __shared__ unsigned short AsL[128 * 64];
    __shared__ unsigned short BsH[128 * 64];
    __shared__ unsigned short BsL[128 * 64];
    const int tid = threadIdx.x;
    const int wid = tid >> 6, lane = tid & 63;
    const int bm = blockIdx.x << 7;
    const int bn = blockIdx.y << 7;
    const int b  = blockIdx.z;
    const unsigned short* XeB = Xe + (((size_t)b * MM + bm) << 10);
    const unsigned short* YeB = Ye + (((size_t)b * NN + bn) << 10);

    f32x4 acc1[4][4];   // Ah*Bh
    f32x4 acc2[4][4];   // Ah*Bl' + Al'*Bh   (carries 2^12 factor)
#pragma unroll
    for (int i = 0; i < 4; ++i)
#pragma unroll
        for (int j = 0; j < 4; ++j) {
            acc1[i][j] = (f32x4){0.f, 0.f, 0.f, 0.f};
            acc2[i][j] = (f32x4){0.f, 0.f, 0.f, 0.f};
        }

    const int wr = (wid >> 1) << 6;
    const int wc = (wid & 1) << 6;
    const int l15 = lane & 15;
    const int xorv = (lane & 7) << 4;
    const int khalf = (lane >> 4) << 4;
    int rbA[4], rbB[4];
#pragma unroll
    for (int i = 0; i < 4; ++i) {
        rbA[i] = (wr + i * 16 + l15) << 7;
        rbB[i] = (wc + i * 16 + l15) << 7;
    }

    int srow[4], scs[4], sldsb[4];
#pragma unroll
    for (int q = 0; q < 4; ++q) {
        const int cl = q * 256 + tid;
        srow[q]  = cl >> 3;
        scs[q]   = ((cl & 7) ^ (srow[q] & 7)) << 3;
        sldsb[q] = (q * 256 + wid * 64) << 4;
    }

    for (int st = 0; st < 8; ++st) {
        const int kin = st << 6;
#pragma unroll
        for (int q = 0; q < 4; ++q) {
            const size_t rb = (size_t)srow[q] << 10;
            __builtin_amdgcn_global_load_lds(
                (const GLOBAL_AS void*)(XeB + rb + kin + scs[q]),
                (LDS_AS void*)((char*)AsH + sldsb[q]), 16, 0, 0);
            __builtin_amdgcn_global_load_lds(
                (const GLOBAL_AS void*)(XeB + rb + 512 + kin + scs[q]),
                (LDS_AS void*)((char*)AsL + sldsb[q]), 16, 0, 0);
            __builtin_amdgcn_global_load_lds(
                (const GLOBAL_AS void*)(YeB + rb + kin + scs[q]),
                (LDS_AS void*)((char*)BsH + sldsb[q]), 16, 0, 0);
            __builtin_amdgcn_global_load_lds(
                (const GLOBAL_AS void*)(YeB + rb + 512 + kin + scs[q]),
                (LDS_AS void*)((char*)BsL + sldsb[q]), 16, 0, 0);
        }
        __syncthreads();
#pragma unroll
        for (int ks = 0; ks < 2; ++ks) {
            const int cb = ((ks << 6) + khalf) ^ xorv;
            short8 ah[4], bh[4], tt[4];
#pragma unroll
            for (int i = 0; i < 4; ++i) {
                ah[i] = *(const short8*)((const char*)AsH + rbA[i] + cb);
                bh[i] = *(const short8*)((const char*)BsH + rbB[i] + cb);
                tt[i] = *(const short8*)((const char*)BsL + rbB[i] + cb);
            }
#pragma unroll
            for (int i = 0; i < 4; ++i)
#pragma unroll
                for (int j = 0; j < 4; ++j) {
                    acc1[i][j] = __builtin_amdgcn_mfma_f32_16x16x32_f16(
                        ah[i], bh[j], acc1[i][j], 0, 0, 0);
                    acc2[i][j] = __builtin_amdgcn_mfma_f32_16x16x32_f16(
                        ah[i], tt[j], acc2[i][j], 0, 0, 0);
                }
#pragma unroll
            for (int i = 0; i < 4; ++i)
                tt[i] = *(const short8*)((const char*)AsL + rbA[i] + cb);
#pragma unroll
            for (int i = 0; i < 4; ++i)
#pragma unroll
                for (int j = 0; j < 4; ++j)
                    acc2[i][j] = __builtin_amdgcn_mfma_f32_16x16x32_f16(
                        tt[i], bh[j], acc2[i][j], 0, 0, 0);
        }
        __syncthreads();
    }
    const float scale = 0.04419417382415922f;
    float* Cb = C + (((size_t)b * MM) << 9);
    const int r0 = (lane >> 4) << 2;
#pragma unroll
    for (int i = 0; i < 4; ++i) {
        const int grow = bm + wr + i * 16 + r0;
#pragma unroll
        for (int j = 0; j < 4; ++j) {
            const int gcol = bn + wc + j * 16 + l15;
#pragma unroll
            for (int r = 0; r < 4; ++r)
                Cb[((size_t)(grow + r) << 9) + gcol] =
                    (acc1[i][j][r] + acc2[i][j][r] * LO_INV) * scale;
        }
    }
}

// ---- small-K fp32 GEMM (g scores, K=33) ----
__global__ __launch_bounds__(256) void gemm_nt(
    const float* __restrict__ X, const float* __restrict__ Y,
    float* __restrict__ C, int K, float scale)
{
    __shared__ float As[16][68];
    __shared__ float Bs[16][68];
    const int bm = blockIdx.x * 64;
    const int bn = blockIdx.y * 64;
    const int b  = blockIdx.z;
    const float* Xb = X + (size_t)b * MM * K;
    const float* Yb = Y + (size_t)b * NN * K;
    const int tid  = threadIdx.x;
    const int row4 = tid >> 2;
    const int kq   = (tid & 3) << 2;
    const int tx = tid & 15, ty = tid >> 4;
    float acc[4][4] = {};
    for (int k0 = 0; k0 < K; k0 += 16) {
#pragma unroll
        for (int j = 0; j < 4; ++j) {
            int k = k0 + kq + j;
            As[kq + j][row4] = (k < K) ? Xb[(size_t)(bm + row4) * K + k] : 0.0f;
            Bs[kq + j][row4] = (k < K) ? Yb[(size_t)(bn + row4) * K + k] : 0.0f;
        }
        __syncthreads();
#pragma unroll
        for (int k = 0; k < 16; ++k) {
            const float4 a4 = *(const float4*)&As[k][ty << 2];
            const float4 b4 = *(const float4*)&Bs[k][tx << 2];
            const float a[4]  = {a4.x, a4.y, a4.z, a4.w};
            const float bv[4] = {b4.x, b4.y, b4.z, b4.w};
#pragma unroll
            for (int i = 0; i < 4; ++i)
#pragma unroll
                for (int j = 0; j < 4; ++j)
                    acc[i][j] = fmaf(a[i], bv[j], acc[i][j]);
        }
        __syncthreads();
    }
    float* Cb = C + ((size_t)b * MM + bm) * NN + bn;
#pragma unroll
    for (int i = 0; i < 4; ++i) {
        float4 v = make_float4(acc[i][0] * scale, acc[i][1] * scale,
                               acc[i][2] * scale, acc[i][3] * scale);
        *(float4*)&Cb[(size_t)(ty * 4 + i) * NN + (tx << 2)] = v;
    }
}

// ---- fused sinkhorn iteration: r = log sum exp(A - c) in-LDS (max-free: |args| << 88),
// ---- then col partials sum_m exp(A - r) ----
__global__ __launch_bounds__(256) void sinkhorn_fused(
    const float* __restrict__ Af, const float* __restrict__ Ag,
    const float* __restrict__ cf, const float* __restrict__ cg,
    float* __restrict__ pf, float* __restrict__ pg)
{
    __shared__ float At[SROWS][512];
    __shared__ float cs[512];
    __shared__ float rs[SROWS];
    const int t = blockIdx.z, b = blockIdx.y, ch = blockIdx.x;
    const float* __restrict__ A = t ? Ag : Af;
    const float* __restrict__ c = t ? cg : cf;
    float* __restrict__ p = t ? pg : pf;
    const int tid = threadIdx.x;
    const float* Ab = A + (((size_t)b * MM + ch * SROWS) << 9);
    cs[tid]       = c[(b << 9) + tid];
    cs[tid + 256] = c[(b << 9) + tid + 256];
#pragma unroll
    for (int q = 0; q < 8; ++q) {
        const int f = (q * 256 + tid) << 2;
        *(float4*)&((float*)At)[f] = *(const float4*)&Ab[f];
    }
    __syncthreads();
    const int wv = tid >> 6, ln = tid & 63;
#pragma unroll
    for (int rr = 0; rr < 4; ++rr) {
        const int r = wv * 4 + rr;
        const float4 x0 = *(const float4*)&At[r][ln * 8];
        const float4 x1 = *(const float4*)&At[r][ln * 8 + 4];
        const float4 c0 = *(const float4*)&cs[ln * 8];
        const float4 c1 = *(const float4*)&cs[ln * 8 + 4];
        float S = __expf(x0.x - c0.x) + __expf(x0.y - c0.y)
                + __expf(x0.z - c0.z) + __expf(x0.w - c0.w)
                + __expf(x1.x - c1.x) + __expf(x1.y - c1.y)
                + __expf(x1.z - c1.z) + __expf(x1.w - c1.w);
#pragma unroll
        for (int s = 32; s; s >>= 1) S += __shfl_xor(S, s);
        if (ln == 0) rs[r] = __logf(S);
    }
    __syncthreads();
    float S0 = 0.f, S1 = 0.f;
#pragma unroll
    for (int r = 0; r < SROWS; ++r) {
        const float rv = rs[r];
        S0 += __expf(At[r][tid] - rv);
        S1 += __expf(At[r][tid + 256] - rv);
    }
    float* pb = p + (((size_t)b * NCH + ch) << 9);
    pb[tid]       = S0;
    pb[tid + 256] = S1;
}

// ---- combine chunk partials -> c[b,n] = log(sum) ----
__global__ __launch_bounds__(256) void col_combine(
    const float* __restrict__ pf, const float* __restrict__ pg,
    float* __restrict__ cf, float* __restrict__ cg)
{
    __shared__ float red[8][32];
    const int blk = blockIdx.x;                       // 0..127
    const int t = blk >> 6, b = (blk >> 4) & 3, n0 = (blk & 15) << 5;
    const int ng = threadIdx.x & 31, grp = threadIdx.x >> 5;
    const float* p = (t ? pg : pf) + (((size_t)b * NCH) << 9) + n0 + ng;
    float s = 0.f;
    for (int cc = grp; cc < NCH; cc += 8) s += p[(size_t)cc << 9];
    red[grp][ng] = s;
    __syncthreads();
    if (threadIdx.x < 32) {
        float tot = 0.f;
#pragma unroll
        for (int g = 0; g < 8; ++g) tot += red[g][threadIdx.x];
        (t ? cg : cf)[(b << 9) + n0 + threadIdx.x] = __logf(tot);
    }
}

// ---- final: 16 lanes per row, 4 rows per wave, 16 rows per block.
// ---- Per lane: 32 scores (cols gl*4 + q*64 + e). Top-20 loop: static VALU argmax
// ---- tree + butterfly {xor8,xor4: shfl(DS)} {xor2,xor1: DPP quad_perm (VALU)}.
// ---- Gather fused into the loop (no weight arrays); tie-break = lowest index.
__global__ __launch_bounds__(256) void final_k(
    const float* __restrict__ Af, const float* __restrict__ Ag,
    const float* __restrict__ cf, const float* __restrict__ cg,
    const float* __restrict__ node_feats, const float* __restrict__ node_fpfhs,
    const float* __restrict__ xyz_feats,  const float* __restrict__ xyz_fpfhs,
    float* __restrict__ out)
{
    const int tid = threadIdx.x;
    const int wv = tid >> 6, ln = tid & 63;
    const int grp = ln >> 4, gl = ln & 15;
    const int row = (blockIdx.x << 4) + (wv << 2) + grp;   // b*M+m
    const int b = row >> 13;
    const int c0 = gl << 2;

    const float* ArF = Af + ((size_t)row << 9);
    const float* ArG = Ag + ((size_t)row << 9);
    const float* cfb = cf + (b << 9);
    const float* cgb = cg + (b << 9);

    float v[8][4];
#pragma unroll
    for (int q = 0; q < 8; ++q) {
        const int col = c0 + (q << 6);
        const float4 fa = *(const float4*)&ArF[col];
        const float4 ga = *(const float4*)&ArG[col];
        const float4 pa = *(const float4*)&cfb[col];
        const float4 qa = *(const float4*)&cgb[col];
        v[q][0] = fa.x + ga.x - pa.x - qa.x;
        v[q][1] = fa.y + ga.y - pa.y - qa.y;
        v[q][2] = fa.z + ga.z - pa.z - qa.z;
        v[q][3] = fa.w + ga.w - pa.w - qa.w;
    }

    const float* nfB = node_feats + ((size_t)(b << 9) << 9);
    const float* ngB = node_fpfhs + (size_t)(b << 9) * GG;

    float acc[8][4];
#pragma unroll
    for (int q = 0; q < 8; ++q)
#pragma unroll
        for (int e = 0; e < 4; ++e) acc[q][e] = 0.f;
    float ag0 = 0.f, ag1 = 0.f, ag2 = 0.f;
    float mx0 = 0.f, Ssum = 0.f;

#pragma unroll 2
    for (int it = 0; it < TOPK; ++it) {
        // ---- lane-local argmax tree over 32 (left = lower index wins ties) ----
        float tv[8]; int ti[8];
#pragma unroll
        for (int q = 0; q < 8; ++q) {
            const bool l01 = v[q][0] >= v[q][1];
            const float v01 = l01 ? v[q][0] : v[q][1];
            const int   i01 = l01 ? 0 : 1;
            const bool l23 = v[q][2] >= v[q][3];
            const float v23 = l23 ? v[q][2] : v[q][3];
            const int   i23 = l23 ? 2 : 3;
            const bool lq = v01 >= v23;
            tv[q] = lq ? v01 : v23;
            ti[q] = (lq ? i01 : i23) + (q << 6);
        }
#pragma unroll
        for (int s = 4; s; s >>= 1)
#pragma unroll
            for (int k = 0; k < 4; ++k) {
                if (k < s) {
                    const bool L = tv[2 * k] >= tv[2 * k + 1];
                    tv[k] = L ? tv[2 * k] : tv[2 * k + 1];
                    ti[k] = L ? ti[2 * k] : ti[2 * k + 1];
                }
            }
        float bv = tv[0];
        int   bi = ti[0] + c0;
        // ---- butterfly within 16-lane group: xor8, xor4 (DS), xor2, xor1 (DPP) ----
#pragma unroll
        for (int s = 8; s >= 4; s >>= 1) {
            const float ov = __shfl_xor(bv, s);
            const int   oi = __shfl_xor(bi, s);
            const bool tk = (ov > bv) || (ov == bv && oi < bi);
            bv = tk ? ov : bv; bi = tk ? oi : bi;
        }
        {
            const float ov = dppf<0x4E>(bv);
            const int   oi = dppi<0x4E>(bi);
            const bool tk = (ov > bv) || (ov == bv && oi < bi);
            bv = tk ? ov : bv; bi = tk ? oi : bi;
        }
        {
            const float ov = dppf<0xB1>(bv);
            const int   oi = dppi<0xB1>(bi);
            const bool tk = (ov > bv) || (ov == bv && oi < bi);
            bv = tk ? ov : bv; bi = tk ? oi : bi;
        }
        // ---- weight + fused gather ----
        if (it == 0) mx0 = bv;
        const float w = __expf(bv - mx0);
        Ssum += w;
        const float* nf = nfB + ((size_t)bi << 9) + c0;
#pragma unroll
        for (int q = 0; q < 8; ++q) {
            const float4 n = *(const float4*)&nf[q << 6];
            acc[q][0] = fmaf(w, n.x, acc[q][0]);
            acc[q][1] = fmaf(w, n.y, acc[q][1]);
            acc[q][2] = fmaf(w, n.z, acc[q][2]);
            acc[q][3] = fmaf(w, n.w, acc[q][3]);
        }
        const float* ng = ngB + (size_t)bi * GG;
        ag0 = fmaf(w, ng[gl], ag0);
        ag1 = fmaf(w, ng[gl + 16], ag1);
        ag2 = fmaf(w, ng[32], ag2);
        // ---- remove selected element (only owning lane matches) ----
        const int rel = bi - c0;
#pragma unroll
        for (int q = 0; q < 8; ++q)
#pragma unroll
            for (int e = 0; e < 4; ++e)
                if (rel == (q << 6) + e) v[q][e] = -INFINITY;
    }

    const float inv = 1.0f / Ssum;
    const float* xf = xyz_feats + ((size_t)row << 9) + c0;
    float* of = out + ((size_t)row << 9) + c0;
#pragma unroll
    for (int q = 0; q < 8; ++q) {
        const float4 x = *(const float4*)&xf[q << 6];
        float4 o;
        o.x = (acc[q][0] * inv + x.x) * 0.5f;
        o.y = (acc[q][1] * inv + x.y) * 0.5f;
        o.z = (acc[q][2] * inv + x.z) * 0.5f;
        o.w = (acc[q][3] * inv + x.w) * 0.5f;
        *(float4*)&of[q << 6] = o;
    }
    const float* xg = xyz_fpfhs + (size_t)row * GG;
    float* og = out + (size_t)BB * MM * DD + (size_t)row * GG;
    og[gl]      = (ag0 * inv + xg[gl]) * 0.5f;
    og[gl + 16] = (ag1 * inv + xg[gl + 16]) * 0.5f;
    if (gl == 0) og[32] = (ag2 * inv + xg[32]) * 0.5f;
}

extern "C" void kernel_launch(void* const* d_in, const int* in_sizes, int n_in,
                              void* d_out, int out_size, void* d_ws, size_t ws_size,
                              hipStream_t stream)
{
    (void)in_sizes; (void)n_in; (void)out_size; (void)ws_size;
    const float* node_feats = (const float*)d_in[2];
    const float* xyz_feats  = (const float*)d_in[3];
    const float* node_fpfhs = (const float*)d_in[4];
    const float* xyz_fpfhs  = (const float*)d_in[5];

    float* ws = (float*)d_ws;
    float* Af = ws;                                  // B*M*N f32
    float* Ag = Af + (size_t)BB * MM * NN;           // B*M*N f32  (aliased: Xe f16 before g-gemm)
    float* cf = Ag + (size_t)BB * MM * NN;           // B*N
    float* cg = cf + BB * NN;                        // B*N
    float* pf = cg + BB * NN;                        // B*NCH*N f32 (aliased: Ye f16 before sinkhorn)
    float* pg = pf + (size_t)BB * NCH * NN;          // B*NCH*N f32
    unsigned short* Xe = (unsigned short*)Ag;        // B*M*1024 f16 == Ag bytes exactly
    unsigned short* Ye = (unsigned short*)pf;        // B*N*1024 f16 == pf bytes exactly
    float* out = (float*)d_out;

    // 1) split fp32 -> f16 hi/lo' (lo scaled 2^12 so every limb is normal-range f16)
    split_hilo<<<dim3(16384), 256, 0, stream>>>(xyz_feats, Xe);
    split_hilo<<<dim3(1024),  256, 0, stream>>>(node_feats, Ye);
    // 2) f-scores via f16 MFMA, 3-term scaled split (reads Xe/Ye, writes Af)
    gemm_f_mfma<<<dim3(MM / 128, NN / 128, BB), 256, 0, stream>>>(Xe, Ye, Af);
    // 3) g-scores fp32 (overwrites Xe region with Ag — Xe is dead now)
    gemm_nt<<<dim3(MM / 64, NN / 64, BB), 256, 0, stream>>>(
        xyz_fpfhs, node_fpfhs, Ag, 33, 0.17407765595569785f);
    // 4) c potentials start at 0
    hipMemsetAsync(cf, 0, 2 * BB * NN * sizeof(float), stream);
    // 5) sinkhorn (fused row+col per iteration; first pf write kills Ye — dead)
    for (int it = 0; it < NITER; ++it) {
        sinkhorn_fused<<<dim3(NCH, BB, 2), 256, 0, stream>>>(Af, Ag, cf, cg, pf, pg);
        col_combine<<<dim3(128), 256, 0, stream>>>(pf, pg, cf, cg);
    }
    // 6) top-k + gather: 16 lanes/row, 16 rows/block
    final_k<<<dim3(BB * MM / 16), 256, 0, stream>>>(Af, Ag, cf, cg, node_feats, node_fpfhs,
                                                    xyz_feats, xyz_fpfhs, out);
}